// Round 1
// 429.645 us; speedup vs baseline: 1.0218x; 1.0218x over previous
//
#include <hip/hip_runtime.h>

// VectorQuantizer: N=16384 rows, C=256, K=8192. inputs fp32, outputs fp32
// (z_q 4194304 ++ indices 16384 ++ loss 1). r10 (barrier-free 128-row kMF)
// passed bit-exact at 439 us; kMF was 300 us with MfmaUtil 9.3%, Occupancy
// 20.5% -- latency-bound: 69 KB LDS caps at 2 blocks/CU (2 waves/SIMD), so
// the scattered 16B B-frag global loads (~200 cyc L1/L2) are unhidden.
// r11: 64-row blocks (As[64][264] = 33.8 KB -> 4 blocks/CU, 4 waves/SIMD).
// Per-wave inner shape kept IDENTICAL to r10 (64 rows x 64 cands, acc[4][4],
// 4:1 MFMA:B-load): the wr row-split is removed, each of the 4 waves owns a
// 64-cand group per cc, cc loop 16->8, grid 512->1024. Exact path
// (sequential-fmaf chain, u64 key tie-break) byte-identical to r9/r10.
//
// margin_n = 2e-5*sqrt(A_n) + 4e-5; flag iff R~ + margin >= rowRunningMax
// (monotone LDS atomicMax; stale threshold only over-flags => safe).
//
// Scratch in z_q float region of d_out (kZQ overwrites last); no d_ws.

#define N_ROWS 16384
#define K_CAND 8192
#define CDIM   256
#define NELEM  4194304

#define SA_FLT   0          // A[16384] fp32 (numpy-pairwise-exact)
#define SK_FLT   16384      // keys u64[16384]
#define SL_FLT   49152      // lossAcc double
#define SQC_FLT  49160      // qcount u32[1024]
#define SBB_FLT  50184      // -B~ f32[8192]
#define SQ_FLT   58384      // queue u32[1024*1280]
#define SFB_FLT  1369104    // fbf = bf16(2*f)[16384][256] as u16
#define SEB_FLT  3466256    // ebf = bf16(e)[8192][256] as u16  (ends 3990544 < NELEM)
#define QCAP     1280

typedef __attribute__((ext_vector_type(8))) short short8;
typedef __attribute__((ext_vector_type(4))) float f32x4;

__device__ __forceinline__ unsigned short f2bf_rne(float x) {
    unsigned u = __float_as_uint(x);
    return (unsigned short)((u + 0x7fffu + ((u >> 16) & 1u)) >> 16);
}
__device__ __forceinline__ float bf2f(unsigned short u) {
    return __uint_as_float(((unsigned)u) << 16);
}
// monotone float->u32 map (handles negatives)
__device__ __forceinline__ unsigned ordU(float f) {
    unsigned u = __float_as_uint(f);
    return u ^ (((int)u >> 31) | 0x80000000u);
}

// exact ref-chain distance + key atomicMin (bit-identical to r6/r9 semantics)
__device__ __forceinline__ void exact_eval(const float* __restrict__ hs,
                                           const float* __restrict__ emb,
                                           const float* __restrict__ A,
                                           unsigned long long* keys,
                                           int row, int cand) {
    int b = row >> 10, yx = row & 1023;
    const float* fp = hs + ((size_t)b << 18) + yx;
    const float* ep = emb + ((size_t)cand << 8);
    float acc = 0.f;
    for (int c = 0; c < 256; ++c)
        acc = fmaf(fp[(size_t)c << 10], ep[c], acc);
    float d = __fsub_rn(A[row], __fadd_rn(acc, acc));
    unsigned long long key =
        ((unsigned long long)__float_as_uint(d) << 32) | (unsigned)cand;
    atomicMin(&keys[row], key);
}

// ---- kA: numpy-pairwise-exact A[n]; init keys + loss -----------------------
__global__ void kA(const float* __restrict__ hs, float* __restrict__ out) {
    float* A = out + SA_FLT;
    unsigned long long* keys = (unsigned long long*)(out + SK_FLT);
    int n = blockIdx.x * 256 + threadIdx.x;
    keys[n] = ~0ull;
    if (n == 0) *(double*)(out + SL_FLT) = 0.0;
    int b = n >> 10, yx = n & 1023;
    const float* base = hs + ((size_t)b << 18) + yx;
    float hsum[2];
    for (int h = 0; h < 2; ++h) {
        float r[8];
        #pragma unroll
        for (int j = 0; j < 8; ++j) {
            float x = base[(size_t)(h * 128 + j) << 10];
            r[j] = __fmul_rn(x, x);
        }
        for (int i = 8; i < 128; i += 8) {
            #pragma unroll
            for (int j = 0; j < 8; ++j) {
                float x = base[(size_t)(h * 128 + i + j) << 10];
                r[j] = __fadd_rn(r[j], __fmul_rn(x, x));
            }
        }
        hsum[h] = __fadd_rn(
            __fadd_rn(__fadd_rn(r[0], r[1]), __fadd_rn(r[2], r[3])),
            __fadd_rn(__fadd_rn(r[4], r[5]), __fadd_rn(r[6], r[7])));
    }
    A[n] = __fadd_rn(hsum[0], hsum[1]);
}

// ---- kFbf: (b,c,yx) -> bf16(2*f)[n][c] via LDS transpose -------------------
__global__ void kFbf(const float* __restrict__ hs, float* __restrict__ out) {
    unsigned short* fbf = (unsigned short*)(out + SFB_FLT);
    __shared__ float T[64][65];
    int blk = blockIdx.x;                 // 16 b x 4 cBlk x 16 yBlk = 1024
    int b = blk >> 6, cB = (blk >> 4) & 3, yB = blk & 15;
    int t = threadIdx.x;
    int yl = t & 63, ch = t >> 6;
    const float* src = hs + ((size_t)b << 18) + (((size_t)cB * 64) << 10) + yB * 64 + yl;
    #pragma unroll
    for (int i = 0; i < 16; ++i) {
        int c = ch * 16 + i;
        T[c][yl] = src[(size_t)c << 10];
    }
    __syncthreads();
    int yr = t >> 2, cs = (t & 3) * 16;
    short8 v0, v1;
    #pragma unroll
    for (int j = 0; j < 8; ++j) {
        v0[j] = (short)f2bf_rne(2.0f * T[cs + j][yr]);
        v1[j] = (short)f2bf_rne(2.0f * T[cs + 8 + j][yr]);
    }
    unsigned short* dst = fbf + (((size_t)(b * 1024 + yB * 64 + yr)) << 8) + cB * 64 + cs;
    *(short8*)dst = v0;
    *(short8*)(dst + 8) = v1;
}

// ---- kEbf: bf16(e)[cand][c] + (-B~) ---------------------------------------
__global__ void kEbf(const float* __restrict__ emb, float* __restrict__ out) {
    unsigned short* ebf = (unsigned short*)(out + SEB_FLT);
    float* bbfNeg = out + SBB_FLT;
    int cand = blockIdx.x * 256 + threadIdx.x;   // grid 32
    const float* ep = emb + ((size_t)cand << 8);
    unsigned short* dp = ebf + ((size_t)cand << 8);
    float s = 0.f;
    for (int c0 = 0; c0 < 256; c0 += 8) {
        short8 v;
        #pragma unroll
        for (int j = 0; j < 8; ++j) {
            unsigned short bb = f2bf_rne(ep[c0 + j]);
            v[j] = (short)bb;
            float eh = bf2f(bb);
            s = fmaf(eh, eh, s);
        }
        *(short8*)(dp + c0) = v;
    }
    bbfNeg[cand] = -s;
}

// ---- kMF: MFMA screening (barrier-free K-loop) + flags + exact re-rank -----
// r11: 64-row blocks, 34 KB LDS -> 4 blocks/CU. grid 1024 = 256 rowBlk x 4
// candSplit. Each of 4 waves owns a 64-cand group per cc; cc loop = 8.
__global__ __launch_bounds__(256, 4) void kMF(const float* __restrict__ hs,
                                              const float* __restrict__ emb,
                                              float* __restrict__ out) {
    const float* A = out + SA_FLT;
    unsigned long long* keys = (unsigned long long*)(out + SK_FLT);
    unsigned* qcount = (unsigned*)(out + SQC_FLT);
    const float* bbfNeg = out + SBB_FLT;
    unsigned* queue = (unsigned*)(out + SQ_FLT);
    const unsigned short* fbf = (const unsigned short*)(out + SFB_FLT);
    const unsigned short* ebf = (const unsigned short*)(out + SEB_FLT);

    __shared__ short As[64][264];         // full 256-k A-tile, stride 132 dw
    __shared__ unsigned rowMaxOrd[64];
    __shared__ float margLds[64];
    __shared__ int lqn;

    const int t = threadIdx.x, blk = blockIdx.x;
    const int row0 = (blk >> 2) * 64;
    const int candSplit = (blk & 3) * 2048;
    const int lane = t & 63, wid = t >> 6;
    const int quad = lane >> 4, l15 = lane & 15;
    unsigned* qBlk = queue + (size_t)blk * QCAP;

    if (t < 64) {
        rowMaxOrd[t] = 0u;
        margLds[t] = 2.0e-5f * sqrtf(A[row0 + t]) + 4.0e-5f;
    }
    if (t == 0) lqn = 0;

    // stage full A-tile ONCE: coalesced 16-B global loads, linear->2D LDS
    {
        const unsigned short* src = fbf + ((size_t)row0 << 8);
        #pragma unroll
        for (int i = 0; i < 8; ++i) {
            int idx = (i * 256 + t) * 8;          // linear short offset
            short8 v = *(const short8*)(src + idx);
            *(short8*)&As[idx >> 8][idx & 255] = v;
        }
    }
    __syncthreads();     // the ONLY barrier before the tail

    for (int cc = 0; cc < 8; ++cc) {
        const int candW = candSplit + cc * 256 + wid * 64;
        f32x4 acc[4][4];
        #pragma unroll
        for (int jc = 0; jc < 4; ++jc) {
            float bneg = bbfNeg[candW + jc * 16 + l15];
            #pragma unroll
            for (int m = 0; m < 4; ++m)
                acc[m][jc] = (f32x4){bneg, bneg, bneg, bneg};
        }
        #pragma unroll
        for (int ks = 0; ks < 8; ++ks) {
            short8 bf[4];
            #pragma unroll
            for (int jc = 0; jc < 4; ++jc)
                bf[jc] = *(const short8*)(ebf + (((size_t)(candW + jc * 16 + l15)) << 8)
                                              + ks * 32 + quad * 8);
            #pragma unroll
            for (int m = 0; m < 4; ++m) {
                short8 af = *(const short8*)&As[m * 16 + l15][ks * 32 + quad * 8];
                #pragma unroll
                for (int jc = 0; jc < 4; ++jc)
                    acc[m][jc] = __builtin_amdgcn_mfma_f32_16x16x32_bf16(
                        af, bf[jc], acc[m][jc], 0, 0, 0);
            }
        }
        // flag: per-(m,reg) early-out; ballot consensus so the 16-lane
        // shuffle-max never runs with inactive lanes (garbage-max hazard)
        #pragma unroll
        for (int m = 0; m < 4; ++m)
            #pragma unroll
            for (int reg = 0; reg < 4; ++reg) {
                int rl = m * 16 + quad * 4 + reg;
                float vmax = fmaxf(fmaxf(acc[m][0][reg], acc[m][1][reg]),
                                   fmaxf(acc[m][2][reg], acc[m][3][reg]));
                unsigned th = rowMaxOrd[rl];
                float mg = margLds[rl];
                bool hot = ordU(__fadd_rn(vmax, mg)) >= th;
                unsigned long long bal = __ballot(hot);
                if (((bal >> (quad * 16)) & 0xFFFFull) == 0ull) continue;
                float g = vmax;                       // all 16 lanes active
                g = fmaxf(g, __shfl_xor(g, 1, 16));
                g = fmaxf(g, __shfl_xor(g, 2, 16));
                g = fmaxf(g, __shfl_xor(g, 4, 16));
                g = fmaxf(g, __shfl_xor(g, 8, 16));
                unsigned og = ordU(g);
                if (og > th) { atomicMax(&rowMaxOrd[rl], og); th = og; }
                #pragma unroll
                for (int jc = 0; jc < 4; ++jc) {
                    float x = acc[m][jc][reg];
                    if (ordU(__fadd_rn(x, mg)) >= th) {
                        int slot = atomicAdd(&lqn, 1);
                        if (slot < QCAP)
                            qBlk[slot] = ((unsigned)rl << 13)
                                       | (unsigned)(candW + jc * 16 + l15);
                    }
                }
            }
    }
    __syncthreads();
    if (t == 0) qcount[blk] = (unsigned)lqn;
    int n = lqn; if (n > QCAP) n = QCAP;
    for (int i = t; i < n; i += 256) {
        unsigned e = qBlk[i];
        exact_eval(hs, emb, A, keys, row0 + (int)(e >> 13), (int)(e & 8191u));
    }
}

// ---- kFallback: exact full scan for overflowed blocks (normally no-op) -----
__global__ void kFallback(const float* __restrict__ hs, const float* __restrict__ emb,
                          float* __restrict__ out) {
    unsigned* qcount = (unsigned*)(out + SQC_FLT);
    if (qcount[blockIdx.x] <= QCAP) return;
    const float* A = out + SA_FLT;
    unsigned long long* keys = (unsigned long long*)(out + SK_FLT);
    int row0 = (int)(blockIdx.x >> 2) * 64, cb = (int)(blockIdx.x & 3) * 2048;
    for (int p = threadIdx.x; p < 64 * 2048; p += 256)
        exact_eval(hs, emb, A, keys, row0 + (p >> 11), cb + (p & 2047));
}

// ---- kPost / kLoss / kZQ (unchanged) ---------------------------------------
__global__ void kPost(float* __restrict__ out) {
    const unsigned long long* keys = (const unsigned long long*)(out + SK_FLT);
    double* lossAcc = (double*)(out + SL_FLT);
    __shared__ double sd[256];
    int n = blockIdx.x * 256 + threadIdx.x;
    unsigned long long key = keys[n];
    unsigned idx = (unsigned)(key & 0xffffffffu) & 8191u;
    float d = __uint_as_float((unsigned)(key >> 32));
    out[NELEM + n] = (float)idx;
    sd[threadIdx.x] = (double)d;
    __syncthreads();
    for (int s = 128; s > 0; s >>= 1) {
        if (threadIdx.x < s) sd[threadIdx.x] += sd[threadIdx.x + s];
        __syncthreads();
    }
    if (threadIdx.x == 0) atomicAdd(lossAcc, sd[0]);
}

__global__ void kLoss(float* __restrict__ out) {
    if (threadIdx.x == 0) {
        double loss = 1.25 * (*(const double*)(out + SL_FLT)) / (double)NELEM;
        out[NELEM + N_ROWS] = (float)loss;
    }
}

__global__ void kZQ(const float* __restrict__ hs, const float* __restrict__ emb,
                    float* __restrict__ out) {
    int o = blockIdx.x * 256 + threadIdx.x;
    int n = (o & 1023) | ((o >> 18) << 10);
    int c = (o >> 10) & 255;
    unsigned idx = (unsigned)out[NELEM + n] & 8191u;
    float e = emb[((size_t)idx << 8) + c];
    float h = hs[o];
    out[o] = __fadd_rn(h, __fsub_rn(e, h));
}

extern "C" void kernel_launch(void* const* d_in, const int* in_sizes, int n_in,
                              void* d_out, int out_size, void* d_ws, size_t ws_size,
                              hipStream_t stream) {
    const float* hs  = (const float*)d_in[0];
    const float* emb = (const float*)d_in[1];
    float* out = (float*)d_out;

    kA<<<N_ROWS / 256, 256, 0, stream>>>(hs, out);
    kFbf<<<1024, 256, 0, stream>>>(hs, out);
    kEbf<<<K_CAND / 256, 256, 0, stream>>>(emb, out);
    kMF<<<1024, 256, 0, stream>>>(hs, emb, out);
    kFallback<<<1024, 256, 0, stream>>>(hs, emb, out);
    kPost<<<N_ROWS / 256, 256, 0, stream>>>(out);
    kLoss<<<1, 64, 0, stream>>>(out);
    kZQ<<<NELEM / 256, 256, 0, stream>>>(hs, emb, out);
}

// Round 2
// 374.335 us; speedup vs baseline: 1.1728x; 1.1478x over previous
//
#include <hip/hip_runtime.h>

// VectorQuantizer: N=16384 rows, C=256, K=8192. inputs fp32, outputs fp32
// (z_q 4194304 ++ indices 16384 ++ loss 1). r11 (64-row blocks, 4 blk/CU)
// passed bit-exact at 430 us; kMF 286 us but MfmaUtil stayed 9.9% while
// occupancy doubled -> NOT wave-starved; bottleneck is vector-mem
// transaction throughput: B-frag loads stride 512B across cands => each
// global_load_dwordx4 splits into 16 lines (4x coalesced minimum).
// r12: ebf stored in 16-cand panel layout ebf2[g][kc][cl] (g=cand>>4,
// kc=k-chunk, cl=cand&15) so a wave's (jc,ks) B-frag load is one contiguous
// 1KB block (4 transactions). Same bytes -> same lanes: MFMA inputs
// bit-identical. All 32 B-loads of a cc hoisted into regs (bfA[4][8],
// static idx) so each cc pays ~1 load latency, not 8. Exact path
// (sequential-fmaf chain, u64 key tie-break) byte-identical to r9-r11.
//
// margin_n = 2e-5*sqrt(A_n) + 4e-5; flag iff R~ + margin >= rowRunningMax
// (monotone LDS atomicMax; stale threshold only over-flags => safe).
//
// Scratch in z_q float region of d_out (kZQ overwrites last); no d_ws.

#define N_ROWS 16384
#define K_CAND 8192
#define CDIM   256
#define NELEM  4194304

#define SA_FLT   0          // A[16384] fp32 (numpy-pairwise-exact)
#define SK_FLT   16384      // keys u64[16384]
#define SL_FLT   49152      // lossAcc double
#define SQC_FLT  49160      // qcount u32[1024]
#define SBB_FLT  50184      // -B~ f32[8192]
#define SQ_FLT   58384      // queue u32[1024*1280]
#define SFB_FLT  1369104    // fbf = bf16(2*f)[16384][256] as u16
#define SEB_FLT  3466256    // ebf2 = bf16(e) 16-cand panels (ends 3990544 < NELEM)
#define QCAP     1280

typedef __attribute__((ext_vector_type(8))) short short8;
typedef __attribute__((ext_vector_type(4))) float f32x4;

__device__ __forceinline__ unsigned short f2bf_rne(float x) {
    unsigned u = __float_as_uint(x);
    return (unsigned short)((u + 0x7fffu + ((u >> 16) & 1u)) >> 16);
}
__device__ __forceinline__ float bf2f(unsigned short u) {
    return __uint_as_float(((unsigned)u) << 16);
}
// monotone float->u32 map (handles negatives)
__device__ __forceinline__ unsigned ordU(float f) {
    unsigned u = __float_as_uint(f);
    return u ^ (((int)u >> 31) | 0x80000000u);
}

// exact ref-chain distance + key atomicMin (bit-identical to r6/r9 semantics)
__device__ __forceinline__ void exact_eval(const float* __restrict__ hs,
                                           const float* __restrict__ emb,
                                           const float* __restrict__ A,
                                           unsigned long long* keys,
                                           int row, int cand) {
    int b = row >> 10, yx = row & 1023;
    const float* fp = hs + ((size_t)b << 18) + yx;
    const float* ep = emb + ((size_t)cand << 8);
    float acc = 0.f;
    for (int c = 0; c < 256; ++c)
        acc = fmaf(fp[(size_t)c << 10], ep[c], acc);
    float d = __fsub_rn(A[row], __fadd_rn(acc, acc));
    unsigned long long key =
        ((unsigned long long)__float_as_uint(d) << 32) | (unsigned)cand;
    atomicMin(&keys[row], key);
}

// ---- kA: numpy-pairwise-exact A[n]; init keys + loss -----------------------
__global__ void kA(const float* __restrict__ hs, float* __restrict__ out) {
    float* A = out + SA_FLT;
    unsigned long long* keys = (unsigned long long*)(out + SK_FLT);
    int n = blockIdx.x * 256 + threadIdx.x;
    keys[n] = ~0ull;
    if (n == 0) *(double*)(out + SL_FLT) = 0.0;
    int b = n >> 10, yx = n & 1023;
    const float* base = hs + ((size_t)b << 18) + yx;
    float hsum[2];
    for (int h = 0; h < 2; ++h) {
        float r[8];
        #pragma unroll
        for (int j = 0; j < 8; ++j) {
            float x = base[(size_t)(h * 128 + j) << 10];
            r[j] = __fmul_rn(x, x);
        }
        for (int i = 8; i < 128; i += 8) {
            #pragma unroll
            for (int j = 0; j < 8; ++j) {
                float x = base[(size_t)(h * 128 + i + j) << 10];
                r[j] = __fadd_rn(r[j], __fmul_rn(x, x));
            }
        }
        hsum[h] = __fadd_rn(
            __fadd_rn(__fadd_rn(r[0], r[1]), __fadd_rn(r[2], r[3])),
            __fadd_rn(__fadd_rn(r[4], r[5]), __fadd_rn(r[6], r[7])));
    }
    A[n] = __fadd_rn(hsum[0], hsum[1]);
}

// ---- kFbf: (b,c,yx) -> bf16(2*f)[n][c] via LDS transpose -------------------
__global__ void kFbf(const float* __restrict__ hs, float* __restrict__ out) {
    unsigned short* fbf = (unsigned short*)(out + SFB_FLT);
    __shared__ float T[64][65];
    int blk = blockIdx.x;                 // 16 b x 4 cBlk x 16 yBlk = 1024
    int b = blk >> 6, cB = (blk >> 4) & 3, yB = blk & 15;
    int t = threadIdx.x;
    int yl = t & 63, ch = t >> 6;
    const float* src = hs + ((size_t)b << 18) + (((size_t)cB * 64) << 10) + yB * 64 + yl;
    #pragma unroll
    for (int i = 0; i < 16; ++i) {
        int c = ch * 16 + i;
        T[c][yl] = src[(size_t)c << 10];
    }
    __syncthreads();
    int yr = t >> 2, cs = (t & 3) * 16;
    short8 v0, v1;
    #pragma unroll
    for (int j = 0; j < 8; ++j) {
        v0[j] = (short)f2bf_rne(2.0f * T[cs + j][yr]);
        v1[j] = (short)f2bf_rne(2.0f * T[cs + 8 + j][yr]);
    }
    unsigned short* dst = fbf + (((size_t)(b * 1024 + yB * 64 + yr)) << 8) + cB * 64 + cs;
    *(short8*)dst = v0;
    *(short8*)(dst + 8) = v1;
}

// ---- kEbf: bf16(e) -> 16-cand panel layout + (-B~) -------------------------
// ebf2 layout (shorts): g=cand>>4, kc=c0/8 (0..31), cl=cand&15:
//   addr = g*4096 + kc*128 + cl*8   (panel 8KB, chunk row 256B, 16B/cand)
__global__ void kEbf(const float* __restrict__ emb, float* __restrict__ out) {
    unsigned short* ebf = (unsigned short*)(out + SEB_FLT);
    float* bbfNeg = out + SBB_FLT;
    int cand = blockIdx.x * 256 + threadIdx.x;   // grid 32
    const float* ep = emb + ((size_t)cand << 8);
    unsigned short* dp = ebf + (((size_t)(cand >> 4)) << 12) + (cand & 15) * 8;
    float s = 0.f;
    for (int c0 = 0; c0 < 256; c0 += 8) {
        short8 v;
        #pragma unroll
        for (int j = 0; j < 8; ++j) {
            unsigned short bb = f2bf_rne(ep[c0 + j]);
            v[j] = (short)bb;
            float eh = bf2f(bb);
            s = fmaf(eh, eh, s);
        }
        *(short8*)(dp + (c0 >> 3) * 128) = v;
    }
    bbfNeg[cand] = -s;
}

// ---- kMF: MFMA screening (barrier-free K-loop) + flags + exact re-rank -----
// r12: coalesced panel B-loads, all 32 frags of a cc hoisted to registers.
__global__ __launch_bounds__(256, 4) void kMF(const float* __restrict__ hs,
                                              const float* __restrict__ emb,
                                              float* __restrict__ out) {
    const float* A = out + SA_FLT;
    unsigned long long* keys = (unsigned long long*)(out + SK_FLT);
    unsigned* qcount = (unsigned*)(out + SQC_FLT);
    const float* bbfNeg = out + SBB_FLT;
    unsigned* queue = (unsigned*)(out + SQ_FLT);
    const unsigned short* fbf = (const unsigned short*)(out + SFB_FLT);
    const unsigned short* ebf = (const unsigned short*)(out + SEB_FLT);

    __shared__ short As[64][264];         // full 256-k A-tile, stride 132 dw
    __shared__ unsigned rowMaxOrd[64];
    __shared__ float margLds[64];
    __shared__ int lqn;

    const int t = threadIdx.x, blk = blockIdx.x;
    const int row0 = (blk >> 2) * 64;
    const int candSplit = (blk & 3) * 2048;
    const int lane = t & 63, wid = t >> 6;
    const int quad = lane >> 4, l15 = lane & 15;
    unsigned* qBlk = queue + (size_t)blk * QCAP;

    if (t < 64) {
        rowMaxOrd[t] = 0u;
        margLds[t] = 2.0e-5f * sqrtf(A[row0 + t]) + 4.0e-5f;
    }
    if (t == 0) lqn = 0;

    // stage full A-tile ONCE: coalesced 16-B global loads, linear->2D LDS
    {
        const unsigned short* src = fbf + ((size_t)row0 << 8);
        #pragma unroll
        for (int i = 0; i < 8; ++i) {
            int idx = (i * 256 + t) * 8;          // linear short offset
            short8 v = *(const short8*)(src + idx);
            *(short8*)&As[idx >> 8][idx & 255] = v;
        }
    }
    __syncthreads();     // the ONLY barrier before the tail

    for (int cc = 0; cc < 8; ++cc) {
        const int candW = candSplit + cc * 256 + wid * 64;
        // per-wave panel base: lanes (quad,l15) -> contiguous 1KB per (jc,ks)
        const unsigned short* ebW = ebf + (((size_t)candW) << 8)
                                       + quad * 128 + l15 * 8;
        // hoist ALL 32 B-frags of this cc (coalesced, one latency exposure)
        short8 bfA[4][8];
        #pragma unroll
        for (int jc = 0; jc < 4; ++jc)
            #pragma unroll
            for (int ks = 0; ks < 8; ++ks)
                bfA[jc][ks] = *(const short8*)(ebW + jc * 4096 + ks * 512);

        f32x4 acc[4][4];
        #pragma unroll
        for (int jc = 0; jc < 4; ++jc) {
            float bneg = bbfNeg[candW + jc * 16 + l15];
            #pragma unroll
            for (int m = 0; m < 4; ++m)
                acc[m][jc] = (f32x4){bneg, bneg, bneg, bneg};
        }
        #pragma unroll
        for (int ks = 0; ks < 8; ++ks) {
            #pragma unroll
            for (int m = 0; m < 4; ++m) {
                short8 af = *(const short8*)&As[m * 16 + l15][ks * 32 + quad * 8];
                #pragma unroll
                for (int jc = 0; jc < 4; ++jc)
                    acc[m][jc] = __builtin_amdgcn_mfma_f32_16x16x32_bf16(
                        af, bfA[jc][ks], acc[m][jc], 0, 0, 0);
            }
        }
        // flag: per-(m,reg) early-out; ballot consensus so the 16-lane
        // shuffle-max never runs with inactive lanes (garbage-max hazard)
        #pragma unroll
        for (int m = 0; m < 4; ++m)
            #pragma unroll
            for (int reg = 0; reg < 4; ++reg) {
                int rl = m * 16 + quad * 4 + reg;
                float vmax = fmaxf(fmaxf(acc[m][0][reg], acc[m][1][reg]),
                                   fmaxf(acc[m][2][reg], acc[m][3][reg]));
                unsigned th = rowMaxOrd[rl];
                float mg = margLds[rl];
                bool hot = ordU(__fadd_rn(vmax, mg)) >= th;
                unsigned long long bal = __ballot(hot);
                if (((bal >> (quad * 16)) & 0xFFFFull) == 0ull) continue;
                float g = vmax;                       // all 16 lanes active
                g = fmaxf(g, __shfl_xor(g, 1, 16));
                g = fmaxf(g, __shfl_xor(g, 2, 16));
                g = fmaxf(g, __shfl_xor(g, 4, 16));
                g = fmaxf(g, __shfl_xor(g, 8, 16));
                unsigned og = ordU(g);
                if (og > th) { atomicMax(&rowMaxOrd[rl], og); th = og; }
                #pragma unroll
                for (int jc = 0; jc < 4; ++jc) {
                    float x = acc[m][jc][reg];
                    if (ordU(__fadd_rn(x, mg)) >= th) {
                        int slot = atomicAdd(&lqn, 1);
                        if (slot < QCAP)
                            qBlk[slot] = ((unsigned)rl << 13)
                                       | (unsigned)(candW + jc * 16 + l15);
                    }
                }
            }
    }
    __syncthreads();
    if (t == 0) qcount[blk] = (unsigned)lqn;
    int n = lqn; if (n > QCAP) n = QCAP;
    for (int i = t; i < n; i += 256) {
        unsigned e = qBlk[i];
        exact_eval(hs, emb, A, keys, row0 + (int)(e >> 13), (int)(e & 8191u));
    }
}

// ---- kFallback: exact full scan for overflowed blocks (normally no-op) -----
__global__ void kFallback(const float* __restrict__ hs, const float* __restrict__ emb,
                          float* __restrict__ out) {
    unsigned* qcount = (unsigned*)(out + SQC_FLT);
    if (qcount[blockIdx.x] <= QCAP) return;
    const float* A = out + SA_FLT;
    unsigned long long* keys = (unsigned long long*)(out + SK_FLT);
    int row0 = (int)(blockIdx.x >> 2) * 64, cb = (int)(blockIdx.x & 3) * 2048;
    for (int p = threadIdx.x; p < 64 * 2048; p += 256)
        exact_eval(hs, emb, A, keys, row0 + (p >> 11), cb + (p & 2047));
}

// ---- kPost / kLoss / kZQ (unchanged) ---------------------------------------
__global__ void kPost(float* __restrict__ out) {
    const unsigned long long* keys = (const unsigned long long*)(out + SK_FLT);
    double* lossAcc = (double*)(out + SL_FLT);
    __shared__ double sd[256];
    int n = blockIdx.x * 256 + threadIdx.x;
    unsigned long long key = keys[n];
    unsigned idx = (unsigned)(key & 0xffffffffu) & 8191u;
    float d = __uint_as_float((unsigned)(key >> 32));
    out[NELEM + n] = (float)idx;
    sd[threadIdx.x] = (double)d;
    __syncthreads();
    for (int s = 128; s > 0; s >>= 1) {
        if (threadIdx.x < s) sd[threadIdx.x] += sd[threadIdx.x + s];
        __syncthreads();
    }
    if (threadIdx.x == 0) atomicAdd(lossAcc, sd[0]);
}

__global__ void kLoss(float* __restrict__ out) {
    if (threadIdx.x == 0) {
        double loss = 1.25 * (*(const double*)(out + SL_FLT)) / (double)NELEM;
        out[NELEM + N_ROWS] = (float)loss;
    }
}

__global__ void kZQ(const float* __restrict__ hs, const float* __restrict__ emb,
                    float* __restrict__ out) {
    int o = blockIdx.x * 256 + threadIdx.x;
    int n = (o & 1023) | ((o >> 18) << 10);
    int c = (o >> 10) & 255;
    unsigned idx = (unsigned)out[NELEM + n] & 8191u;
    float e = emb[((size_t)idx << 8) + c];
    float h = hs[o];
    out[o] = __fadd_rn(h, __fsub_rn(e, h));
}

extern "C" void kernel_launch(void* const* d_in, const int* in_sizes, int n_in,
                              void* d_out, int out_size, void* d_ws, size_t ws_size,
                              hipStream_t stream) {
    const float* hs  = (const float*)d_in[0];
    const float* emb = (const float*)d_in[1];
    float* out = (float*)d_out;

    kA<<<N_ROWS / 256, 256, 0, stream>>>(hs, out);
    kFbf<<<1024, 256, 0, stream>>>(hs, out);
    kEbf<<<K_CAND / 256, 256, 0, stream>>>(emb, out);
    kMF<<<1024, 256, 0, stream>>>(hs, emb, out);
    kFallback<<<1024, 256, 0, stream>>>(hs, emb, out);
    kPost<<<N_ROWS / 256, 256, 0, stream>>>(out);
    kLoss<<<1, 64, 0, stream>>>(out);
    kZQ<<<NELEM / 256, 256, 0, stream>>>(hs, emb, out);
}